// Round 1
// baseline (165.755 us; speedup 1.0000x reference)
//
#include <hip/hip_runtime.h>
#include <math.h>

// Fused QWZ deformation + Dirichlet/HS-distance kernel.
// Tile: 8 rows x 32 cols of output sites per 256-thread block.
// Halo: +1 row, +1 col (wrapped) -> 9x33 = 297 deformed spinors in LDS.
#define TILE_I 8
#define TILE_J 32
#define HALO_I (TILE_I + 1)   // 9
#define HALO_J (TILE_J + 1)   // 33

__global__ __launch_bounds__(256) void qwz_deform_dirichlet_kernel(
    const float* __restrict__ theta,
    const float* __restrict__ phi,
    const float* __restrict__ psi,
    const float2* __restrict__ sre,   // state_re viewed as [N] float2 (2 spin comps)
    const float2* __restrict__ sim,   // state_im viewed as [N] float2
    float* __restrict__ out,          // [3, mesh, mesh]
    int mesh)
{
    const int N = mesh * mesh;
    __shared__ float4 tile[HALO_I * HALO_J];  // (re0, re1, im0, im1) per site

    const int bi = blockIdx.y * TILE_I;
    const int bj = blockIdx.x * TILE_J;
    const int tid = threadIdx.x;

    // ---- Phase 1: deform halo tile into LDS ----
    for (int l = tid; l < HALO_I * HALO_J; l += 256) {
        int ti = l / HALO_J;
        int tj = l - ti * HALO_J;
        int gi = bi + ti; if (gi >= mesh) gi -= mesh;   // wrap (roll)
        int gj = bj + tj; if (gj >= mesh) gj -= mesh;
        int n = gi * mesh + gj;

        float2 r = sre[n];
        float2 im = sim[n];
        float4 d4;
        if (n == 0) {
            // first site keeps the undeformed state
            d4 = make_float4(r.x, r.y, im.x, im.y);
        } else {
            float th = theta[n - 1], ph = phi[n - 1], ps = psi[n - 1];
            float st, ct, sp, cp, sq, cq;
            __sincosf(th, &st, &ct);
            __sincosf(ph, &sp, &cp);
            __sincosf(ps, &sq, &cq);
            float a = ct * cp;   // su_re diag
            float b = st * cq;   // su_re off-diag magnitude
            float c = ct * sp;   // su_im diag
            float d = st * sq;   // su_im off-diag magnitude
            // su_re = [[a,-b],[b,a]], su_im = [[c,-d],[-d,-c]]
            // d_re = su_re@s_re - su_im@s_im ; d_im = su_re@s_im + su_im@s_re
            d4.x = a * r.x - b * r.y - c * im.x + d * im.y;
            d4.y = b * r.x + a * r.y + d * im.x + c * im.y;
            d4.z = a * im.x - b * im.y + c * r.x - d * r.y;
            d4.w = b * im.x + a * im.y - d * r.x - c * r.y;
        }
        tile[l] = d4;
    }
    __syncthreads();

    // ---- Phase 2: HS distances to 3 neighbors ----
    int ti = tid >> 5;            // /32, 0..7
    int tj = tid & 31;            // %32
    float4 A = tile[ti * HALO_J + tj];
    float4 V = tile[ti * HALO_J + tj + 1];          // (i, j+1)
    float4 H = tile[(ti + 1) * HALO_J + tj];        // (i+1, j)
    float4 D = tile[(ti + 1) * HALO_J + tj + 1];    // (i+1, j+1)

    int gi = bi + ti;   // mesh % TILE_I == 0, mesh % TILE_J == 0 assumed (2048)
    int gj = bj + tj;
    int site = gi * mesh + gj;

    // hs(a,b): rr = <a_re,b_re>+<a_im,b_im>; ri = <a_re,b_im>-<a_im,b_re>
    //          sqrt(|1 - rr^2 - ri^2|)
    {
        float rr = A.x * V.x + A.y * V.y + A.z * V.z + A.w * V.w;
        float ri = A.x * V.z + A.y * V.w - A.z * V.x - A.w * V.y;
        out[site] = sqrtf(fabsf(1.0f - rr * rr - ri * ri));
    }
    {
        float rr = A.x * H.x + A.y * H.y + A.z * H.z + A.w * H.w;
        float ri = A.x * H.z + A.y * H.w - A.z * H.x - A.w * H.y;
        out[N + site] = sqrtf(fabsf(1.0f - rr * rr - ri * ri));
    }
    {
        float rr = A.x * D.x + A.y * D.y + A.z * D.z + A.w * D.w;
        float ri = A.x * D.z + A.y * D.w - A.z * D.x - A.w * D.y;
        out[2 * N + site] = sqrtf(fabsf(1.0f - rr * rr - ri * ri));
    }
}

extern "C" void kernel_launch(void* const* d_in, const int* in_sizes, int n_in,
                              void* d_out, int out_size, void* d_ws, size_t ws_size,
                              hipStream_t stream) {
    const float* theta = (const float*)d_in[0];
    const float* phi   = (const float*)d_in[1];
    const float* psi   = (const float*)d_in[2];
    const float2* sre  = (const float2*)d_in[3];
    const float2* sim  = (const float2*)d_in[4];
    float* out = (float*)d_out;

    int N = in_sizes[0] + 1;                       // theta has N-1 elements
    int mesh = (int)(sqrt((double)N) + 0.5);       // 2048

    dim3 grid(mesh / TILE_J, mesh / TILE_I);       // (64, 256)
    dim3 block(256);
    qwz_deform_dirichlet_kernel<<<grid, block, 0, stream>>>(
        theta, phi, psi, sre, sim, out, mesh);
}

// Round 2
// 163.902 us; speedup vs baseline: 1.0113x; 1.0113x over previous
//
#include <hip/hip_runtime.h>
#include <math.h>

// Fused QWZ deformation + HS-distance kernel, v2.
// 32x32 output tile per 256-thread block; halo 33x33 deformed spinors in LDS.
// Phase 1 stages 5 unrolled batches of global loads (25 loads in flight/thread)
// before any trig; phase 2 computes 4 output rows/thread with LDS row reuse.
#define TILE 32
#define HALO 33            // TILE + 1
#define NHALO (HALO * HALO)  // 1089

__global__ __launch_bounds__(256) void qwz_deform_dirichlet_kernel(
    const float* __restrict__ theta,
    const float* __restrict__ phi,
    const float* __restrict__ psi,
    const float2* __restrict__ sre,   // state_re as [N] float2
    const float2* __restrict__ sim,   // state_im as [N] float2
    float* __restrict__ out,          // [3, mesh, mesh]
    int mesh)
{
    const int N = mesh * mesh;
    __shared__ float4 tile[NHALO];    // (re0, re1, im0, im1) per halo site

    const int bi = blockIdx.y * TILE;
    const int bj = blockIdx.x * TILE;
    const int tid = threadIdx.x;

    // ---- Phase 1a: issue ALL global loads (5 batches, unconditional) ----
    float th[5], ph[5], ps[5];
    float2 r2[5], i2[5];
    int n_arr[5];
#pragma unroll
    for (int k = 0; k < 5; ++k) {
        int l = tid + k * 256;        // 0..1279; >=1089 lanes load junk-but-valid
        int trow = l / HALO;          // 0..38
        int tcol = l - trow * HALO;   // 0..32
        int gi = bi + trow; if (gi >= mesh) gi -= mesh;   // single wrap suffices
        int gj = bj + tcol; if (gj >= mesh) gj -= mesh;
        int n = gi * mesh + gj;
        n_arr[k] = n;
        int an = (n > 0) ? n - 1 : 0; // avoid theta[-1]
        th[k] = theta[an];
        ph[k] = phi[an];
        ps[k] = psi[an];
        r2[k] = sre[n];
        i2[k] = sim[n];
    }

    // ---- Phase 1b: deform + predicated LDS write ----
#pragma unroll
    for (int k = 0; k < 5; ++k) {
        int l = tid + k * 256;
        float st, ct, sp, cp, sq, cq;
        __sincosf(th[k], &st, &ct);
        __sincosf(ph[k], &sp, &cp);
        __sincosf(ps[k], &sq, &cq);
        float a = ct * cp;   // su_re diag
        float b = st * cq;   // su_re off-diag
        float c = ct * sp;   // su_im diag
        float d = st * sq;   // su_im off-diag
        float2 r = r2[k], im = i2[k];
        // d_re = su_re@s_re - su_im@s_im ; d_im = su_re@s_im + su_im@s_re
        float4 d4;
        d4.x = a * r.x - b * r.y - c * im.x + d * im.y;
        d4.y = b * r.x + a * r.y + d * im.x + c * im.y;
        d4.z = a * im.x - b * im.y + c * r.x - d * r.y;
        d4.w = b * im.x + a * im.y - d * r.x - c * r.y;
        if (n_arr[k] == 0)            // site 0 keeps undeformed state
            d4 = make_float4(r.x, r.y, im.x, im.y);
        if (l < NHALO)
            tile[l] = d4;
    }
    __syncthreads();

    // ---- Phase 2: 4 output rows per thread, LDS row reuse ----
    const int trow = (tid >> 5) << 2;  // 0,4,...,28
    const int tcol = tid & 31;

    float4 c0[5], c1[5];
#pragma unroll
    for (int k = 0; k < 5; ++k) {
        c0[k] = tile[(trow + k) * HALO + tcol];
        c1[k] = tile[(trow + k) * HALO + tcol + 1];
    }

#pragma unroll
    for (int k = 0; k < 4; ++k) {
        float4 A = c0[k];
        float4 V = c1[k];          // (i, j+1)
        float4 H = c0[k + 1];      // (i+1, j)
        float4 D = c1[k + 1];      // (i+1, j+1)
        int site = (bi + trow + k) * mesh + (bj + tcol);

        float rr, ri, v, h, d;
        rr = A.x * V.x + A.y * V.y + A.z * V.z + A.w * V.w;
        ri = A.x * V.z + A.y * V.w - A.z * V.x - A.w * V.y;
        v = sqrtf(fabsf(1.0f - rr * rr - ri * ri));
        rr = A.x * H.x + A.y * H.y + A.z * H.z + A.w * H.w;
        ri = A.x * H.z + A.y * H.w - A.z * H.x - A.w * H.y;
        h = sqrtf(fabsf(1.0f - rr * rr - ri * ri));
        rr = A.x * D.x + A.y * D.y + A.z * D.z + A.w * D.w;
        ri = A.x * D.z + A.y * D.w - A.z * D.x - A.w * D.y;
        d = sqrtf(fabsf(1.0f - rr * rr - ri * ri));

        __builtin_nontemporal_store(v, out + site);
        __builtin_nontemporal_store(h, out + N + site);
        __builtin_nontemporal_store(d, out + 2 * N + site);
    }
}

extern "C" void kernel_launch(void* const* d_in, const int* in_sizes, int n_in,
                              void* d_out, int out_size, void* d_ws, size_t ws_size,
                              hipStream_t stream) {
    const float* theta = (const float*)d_in[0];
    const float* phi   = (const float*)d_in[1];
    const float* psi   = (const float*)d_in[2];
    const float2* sre  = (const float2*)d_in[3];
    const float2* sim  = (const float2*)d_in[4];
    float* out = (float*)d_out;

    int N = in_sizes[0] + 1;                       // theta has N-1 elements
    int mesh = (int)(sqrt((double)N) + 0.5);       // 2048

    dim3 grid(mesh / TILE, mesh / TILE);           // (64, 64)
    dim3 block(256);
    qwz_deform_dirichlet_kernel<<<grid, block, 0, stream>>>(
        theta, phi, psi, sre, sim, out, mesh);
}